// Round 18
// baseline (171.667 us; speedup 1.0000x reference)
//
#include <hip/hip_runtime.h>
#include <hip/hip_bf16.h>

typedef unsigned short u16;
typedef int i32x4 __attribute__((ext_vector_type(4)));
typedef int i32x16 __attribute__((ext_vector_type(16)));
typedef signed char s8;

#define NB_RED 256

static __device__ __forceinline__ float tanh_fast(float x) {
    float t = __expf(2.0f * x);
    return 1.0f - 2.0f / (t + 1.0f);
}

// ---------------- min/max reduction (4 tensors) ----------------
__global__ void k_minmax_partial(const float* __restrict__ x, const float* __restrict__ h,
                                 const float* __restrict__ wi, const float* __restrict__ wh,
                                 float* __restrict__ partials) {
    int t = blockIdx.y;
    const float* p = (t == 0) ? x : (t == 1) ? h : (t == 2) ? wi : wh;
    int n4 = ((t < 2) ? (8192 * 1024) : (4096 * 1024)) >> 2;
    float mn = 3.4e38f, mx = -3.4e38f;
    const float4* p4 = (const float4*)p;
    for (int i = blockIdx.x * blockDim.x + threadIdx.x; i < n4; i += gridDim.x * blockDim.x) {
        float4 v = p4[i];
        mn = fminf(mn, fminf(fminf(v.x, v.y), fminf(v.z, v.w)));
        mx = fmaxf(mx, fmaxf(fmaxf(v.x, v.y), fmaxf(v.z, v.w)));
    }
    for (int d = 1; d < 64; d <<= 1) {
        mn = fminf(mn, __shfl_xor(mn, d));
        mx = fmaxf(mx, __shfl_xor(mx, d));
    }
    __shared__ float smn[4], smx[4];
    int wv = threadIdx.x >> 6;
    if ((threadIdx.x & 63) == 0) { smn[wv] = mn; smx[wv] = mx; }
    __syncthreads();
    if (threadIdx.x == 0) {
        mn = fminf(fminf(smn[0], smn[1]), fminf(smn[2], smn[3]));
        mx = fmaxf(fmaxf(smx[0], smx[1]), fmaxf(smx[2], smx[3]));
        partials[(t * NB_RED + blockIdx.x) * 2 + 0] = mn;
        partials[(t * NB_RED + blockIdx.x) * 2 + 1] = mx;
    }
}

__global__ void k_minmax_final(const float* __restrict__ partials, const int* __restrict__ nbits,
                               float* __restrict__ params) {
    int t = blockIdx.x;
    int tid = threadIdx.x;
    float mn = partials[(t * NB_RED + tid) * 2 + 0];
    float mx = partials[(t * NB_RED + tid) * 2 + 1];
    for (int d = 1; d < 64; d <<= 1) {
        mn = fminf(mn, __shfl_xor(mn, d));
        mx = fmaxf(mx, __shfl_xor(mx, d));
    }
    __shared__ float smn[4], smx[4];
    int wv = tid >> 6;
    if ((tid & 63) == 0) { smn[wv] = mn; smx[wv] = mx; }
    __syncthreads();
    if (tid == 0) {
        mn = fminf(fminf(smn[0], smn[1]), fminf(smn[2], smn[3]));
        mx = fmaxf(fmaxf(smx[0], smx[1]), fmaxf(smx[2], smx[3]));
        float qmax = (float)((1u << (*nbits)) - 1u);
        params[t * 2 + 0] = mn;
        params[t * 2 + 1] = (mx - mn) / qmax;
    }
}

static __device__ __forceinline__ int block_reduce_i(int v, int tid) {
    for (int d = 1; d < 64; d <<= 1) v += __shfl_xor(v, d);
    __shared__ int sred[4];
    if ((tid & 63) == 0) sred[tid >> 6] = v;
    __syncthreads();
    return sred[0] + sred[1] + sred[2] + sred[3];
}

// ---- fused quantize (x|h -> A8, W_in|W_h -> W8 permuted) + bias ----
// W permutation (gate-PAIR form for 2x2 wave epilogue exchange):
//   original row = g*1024 + j  ->  prow = (j>>6)*256 + ((j>>5)&1)*128 + g*32 + (j&31)
__global__ void k_quant(const float* __restrict__ x, const float* __restrict__ h,
                        const float* __restrict__ wi, const float* __restrict__ wh,
                        const float* __restrict__ params,
                        const float* __restrict__ b_in, const float* __restrict__ b_h,
                        s8* __restrict__ A8, s8* __restrict__ W8,
                        float* __restrict__ Rax, float* __restrict__ Rah,
                        float* __restrict__ Rbi, float* __restrict__ Rbh,
                        float* __restrict__ bc) {
    int b = blockIdx.x;
    int t = threadIdx.x;
    if (b < 16384) {
        int tsel = b >> 13;            // 0: x, 1: h
        int row = b & 8191;
        const float* src = tsel ? h : x;
        float mn = params[tsel * 2 + 0], s = params[tsel * 2 + 1];
        float4 v = ((const float4*)(src + (size_t)row * 1024))[t];
        int k0 = (int)fminf(255.f, fmaxf(0.f, rintf((v.x - mn) / s)));
        int k1 = (int)fminf(255.f, fmaxf(0.f, rintf((v.y - mn) / s)));
        int k2 = (int)fminf(255.f, fmaxf(0.f, rintf((v.z - mn) / s)));
        int k3 = (int)fminf(255.f, fmaxf(0.f, rintf((v.w - mn) / s)));
        unsigned p = ((unsigned)((k0 - 128) & 0xff)) | ((unsigned)((k1 - 128) & 0xff) << 8) |
                     ((unsigned)((k2 - 128) & 0xff) << 16) | ((unsigned)((k3 - 128) & 0xff) << 24);
        *(unsigned*)(A8 + (size_t)row * 2048 + tsel * 1024 + t * 4) = p;
        int sum = block_reduce_i(k0 + k1 + k2 + k3 - 512, t);
        if (t == 0) (tsel ? Rah : Rax)[row] = (float)sum;
    } else if (b < 24576) {
        int bb = b - 16384;
        int tsel = bb >> 12;           // 0: W_in, 1: W_h
        int row = bb & 4095;           // original row g*1024+j
        const float* src = tsel ? wh : wi;
        float mn = params[(2 + tsel) * 2 + 0], s = params[(2 + tsel) * 2 + 1];
        int g = row >> 10, j = row & 1023;
        int prow = (j >> 6) * 256 + ((j >> 5) & 1) * 128 + g * 32 + (j & 31);
        float4 v = ((const float4*)(src + (size_t)row * 1024))[t];
        int k0 = (int)fminf(255.f, fmaxf(0.f, rintf((v.x - mn) / s)));
        int k1 = (int)fminf(255.f, fmaxf(0.f, rintf((v.y - mn) / s)));
        int k2 = (int)fminf(255.f, fmaxf(0.f, rintf((v.z - mn) / s)));
        int k3 = (int)fminf(255.f, fmaxf(0.f, rintf((v.w - mn) / s)));
        unsigned p = ((unsigned)((k0 - 128) & 0xff)) | ((unsigned)((k1 - 128) & 0xff) << 8) |
                     ((unsigned)((k2 - 128) & 0xff) << 16) | ((unsigned)((k3 - 128) & 0xff) << 24);
        *(unsigned*)(W8 + (size_t)prow * 2048 + tsel * 1024 + t * 4) = p;
        int sum = block_reduce_i(k0 + k1 + k2 + k3 - 512, t);
        if (t == 0) (tsel ? Rbh : Rbi)[prow] = (float)sum;
    } else {
        int n = (b - 24576) * 256 + t;   // permuted col index
        int tIdx = n >> 8, c = n & 255;
        int j = tIdx * 64 + ((c >> 7) & 1) * 32 + (c & 31);
        int g = (c >> 5) & 3;
        bc[n] = b_in[g * 1024 + j] + b_h[g * 1024 + j];
    }
}

// ------- fused i8 GEMM + LSTM (128x256, 2Mx4N waves of 64x64) ---------------
// = R17 structure, + epilogue-head hiding:
//  (a) colt[4] + all epilogue constants hoisted BEFORE the K-loop (bc/Rbi/Rbh
//      are L2-hot; 12 loads leave the tail critical path);
//  (b) c_in[16] and rterm[16] (Rax/Rah) prefetched immediately after the
//      t==30 vmcnt(0) drain -- no counted-vmcnt waits remain, so the 48
//      loads can't perturb the staging pipeline; they overlap the final
//      COMPUTE + partner-exchange barriers.
// All else = R17 (validated absmax 0.015625): 3-buffer ring, stage 2 ahead,
// vmcnt(3) steady, ONE barrier per K-step, single acc + mid-K rescale t==16,
// swizzle f(r)=((r>>1)^(r>>3))&3 inverse-on-source, XCD decode grid 1024,
// gate-pair exchange epilogue, __launch_bounds__(512,4).
__global__ __launch_bounds__(512, 4) void k_gemm_lstm(
    const s8* __restrict__ A8, const s8* __restrict__ W8,
    const float* __restrict__ params, const float* __restrict__ bc,
    const float* __restrict__ Rax, const float* __restrict__ Rah,
    const float* __restrict__ Rbi, const float* __restrict__ Rbh,
    const float* __restrict__ c_in, float* __restrict__ out) {
    __shared__ __align__(16) s8 SH[73728];
#define ASB(B) (SH + (B) * 8192)
#define BSB(B) (SH + 24576 + (B) * 16384)

    const int tid = threadIdx.x;
    const int wave = tid >> 6, lane = tid & 63;
    const int wr = wave >> 2, wc = wave & 3;     // 2M x 4N wave grid
    const int l31 = lane & 31, lh = lane >> 5;

    const int bid = blockIdx.x;
    const int l = bid >> 3;                      // 0..127
    const int bx = l >> 3;                       // 0..15 (N tile, slow)
    const int by = (bid & 7) * 8 + (l & 7);      // 0..63 (M tile)
    const int bm = by * 128, bn = bx * 256;

    const int skb = (((tid & 3) ^ ((tid >> 3) & 3) ^ ((tid >> 5) & 3)) * 16);
    const int q = ((l31 >> 1) ^ (l31 >> 3)) & 3;

    const float sa = params[1], sh = params[3], si = params[5], sw = params[7];
    const float csx = sa * si, csh = sh * sw;
    const float r = csx / csh;

    // ---- epilogue constants + colt hoisted before the K-loop ----
    const float mna = params[0], mnh = params[2], mni = params[4], mnw = params[6];
    const float za = mna + 128.0f * sa, zi = mni + 128.0f * si;
    const float zh = mnh + 128.0f * sh, zw = mnw + 128.0f * sw;
    const float C0 = 1024.0f * (za * zi + zh * zw);
    const float cax = sa * zi, cah = sh * zw;
    const float cbx = si * za, cbh = sw * zh;
    const int P = wc & 1;                        // own gate pair / row-half
    float colt[4];
#pragma unroll
    for (int g = 0; g < 4; ++g) {
        int np = bn + (wc >> 1) * 128 + g * 32 + l31;
        colt[g] = bc[np] + cbx * Rbi[np] + cbh * Rbh[np] + C0;
    }
    const int ub = (bn >> 2) + (wc >> 1) * 32 + l31;   // hidden-unit index

    const s8* pA0 = A8 + (size_t)(bm + (tid >> 2)) * 2048 + skb;
    const s8* pB0 = W8 + (size_t)(bn + (tid >> 2)) * 2048 + skb;
    const s8* pB1 = pB0 + (size_t)128 * 2048;

    i32x16 acc[2][2];
#pragma unroll
    for (int m = 0; m < 2; m++)
#pragma unroll
        for (int n = 0; n < 2; n++) acc[m][n] = (i32x16)0;

#define STAGE(B, T)                                                                               \
    do {                                                                                          \
        __builtin_amdgcn_global_load_lds(                                                         \
            (const __attribute__((address_space(1))) void*)(pA0 + (T) * 64),                      \
            (__attribute__((address_space(3))) void*)(ASB(B) + tid * 16), 16, 0, 0);              \
        __builtin_amdgcn_global_load_lds(                                                         \
            (const __attribute__((address_space(1))) void*)(pB0 + (T) * 64),                      \
            (__attribute__((address_space(3))) void*)(BSB(B) + tid * 16), 16, 0, 0);              \
        __builtin_amdgcn_global_load_lds(                                                         \
            (const __attribute__((address_space(1))) void*)(pB1 + (T) * 64),                      \
            (__attribute__((address_space(3))) void*)(BSB(B) + 8192 + tid * 16), 16, 0, 0);       \
    } while (0)

#define COMPUTE(B)                                                                                \
    do {                                                                                          \
        _Pragma("unroll") for (int ks = 0; ks < 2; ++ks) {                                        \
            const int ro = ((ks * 2 + lh) ^ q) * 16;                                              \
            i32x4 a0 = *(const i32x4*)(ASB(B) + (wr * 64 + l31) * 64 + ro);                       \
            i32x4 a1 = *(const i32x4*)(ASB(B) + (wr * 64 + 32 + l31) * 64 + ro);                  \
            i32x4 b0 = *(const i32x4*)(BSB(B) + (wc * 64 + l31) * 64 + ro);                       \
            i32x4 b1 = *(const i32x4*)(BSB(B) + (wc * 64 + 32 + l31) * 64 + ro);                  \
            acc[0][0] = __builtin_amdgcn_mfma_i32_32x32x32_i8(a0, b0, acc[0][0], 0, 0, 0);        \
            acc[0][1] = __builtin_amdgcn_mfma_i32_32x32x32_i8(a0, b1, acc[0][1], 0, 0, 0);        \
            acc[1][0] = __builtin_amdgcn_mfma_i32_32x32x32_i8(a1, b0, acc[1][0], 0, 0, 0);        \
            acc[1][1] = __builtin_amdgcn_mfma_i32_32x32x32_i8(a1, b1, acc[1][1], 0, 0, 0);        \
        }                                                                                         \
    } while (0)

    STAGE(0, 0);
    STAGE(1, 1);
    asm volatile("s_waitcnt vmcnt(3)" ::: "memory");
    __builtin_amdgcn_s_barrier();

#pragma unroll
    for (int t = 0; t < 30; ++t) {
        STAGE((t + 2) % 3, t + 2);
        if (t == 16) {
#pragma unroll
            for (int m = 0; m < 2; m++)
#pragma unroll
                for (int n = 0; n < 2; n++)
#pragma unroll
                    for (int e = 0; e < 16; e++)
                        acc[m][n][e] = (int)rintf((float)acc[m][n][e] * r);
        }
        COMPUTE(t % 3);
        asm volatile("s_waitcnt vmcnt(3)" ::: "memory");
        __builtin_amdgcn_s_barrier();
    }
    // t = 30: no stage; drain all staging loads
    COMPUTE(0);
    asm volatile("s_waitcnt vmcnt(0)" ::: "memory");
    __builtin_amdgcn_s_barrier();

    // ---- prefetch epilogue operands (c_in + Rax/Rah) while t=31 computes ----
    float cvv[16], rt[16];
#pragma unroll
    for (int j = 0; j < 16; ++j) {
        int row = bm + wr * 64 + P * 32 + 8 * (j >> 2) + 4 * lh + (j & 3);
        cvv[j] = c_in[(size_t)row * 1024 + ub];
        rt[j] = cax * Rax[row] + cah * Rah[row];
    }

    // t = 31 (last K-step)
    COMPUTE(1);

#undef STAGE
#undef COMPUTE

    // ---- epilogue: partner-wave gate exchange through LDS, then LSTM ----
    __syncthreads();   // all waves done reading K-loop buffers

    const int l7 = lane & 7;
    s8* xw = SH + wave * 8192 + lane * 128;          // own slot (64KB total)
    s8* xr = SH + (wave ^ 1) * 8192 + lane * 128;    // partner slot

#define WRX(MIP)                                                              \
    do {                                                                      \
        _Pragma("unroll") for (int ni = 0; ni < 2; ++ni)                      \
            _Pragma("unroll") for (int c2 = 0; c2 < 4; ++c2) {                \
                i32x4 v;                                                      \
                v[0] = acc[MIP][ni][4 * c2 + 0];                              \
                v[1] = acc[MIP][ni][4 * c2 + 1];                              \
                v[2] = acc[MIP][ni][4 * c2 + 2];                              \
                v[3] = acc[MIP][ni][4 * c2 + 3];                              \
                *(i32x4*)(xw + (((ni * 4 + c2) ^ l7) * 16)) = v;              \
            }                                                                 \
    } while (0)
    if (P == 0) WRX(1); else WRX(0);
#undef WRX

    __syncthreads();   // partner writes visible

#define EPI(MIO)                                                              \
    do {                                                                      \
        _Pragma("unroll") for (int c2 = 0; c2 < 4; ++c2) {                    \
            i32x4 q0 = *(const i32x4*)(xr + (((c2) ^ l7) * 16));              \
            i32x4 q1 = *(const i32x4*)(xr + (((4 + c2) ^ l7) * 16));          \
            _Pragma("unroll") for (int e = 0; e < 4; ++e) {                   \
                int j = 4 * c2 + e;                                           \
                int row = bm + wr * 64 + (MIO) * 32 + 8 * c2 + 4 * lh + e;    \
                float gv0, gv1, gv2, gv3;                                     \
                if ((MIO) == 0) {                                             \
                    gv0 = (float)acc[0][0][4 * c2 + e];                       \
                    gv1 = (float)acc[0][1][4 * c2 + e];                       \
                    gv2 = (float)q0[e]; gv3 = (float)q1[e];                   \
                } else {                                                      \
                    gv2 = (float)acc[1][0][4 * c2 + e];                       \
                    gv3 = (float)acc[1][1][4 * c2 + e];                       \
                    gv0 = (float)q0[e]; gv1 = (float)q1[e];                   \
                }                                                             \
                float g0 = colt[0] + rt[j] + csh * gv0;                       \
                float g1 = colt[1] + rt[j] + csh * gv1;                       \
                float g2 = colt[2] + rt[j] + csh * gv2;                       \
                float g3 = colt[3] + rt[j] + csh * gv3;                       \
                float iv = 1.0f / (1.0f + __expf(-g0));                       \
                float fv = 1.0f / (1.0f + __expf(-g1));                       \
                float gg = tanh_fast(g2);                                     \
                float ov = 1.0f / (1.0f + __expf(-g3));                       \
                size_t off = (size_t)row * 1024 + ub;                         \
                float cn = fv * cvv[j] + iv * gg;                             \
                float hn = ov * tanh_fast(cn);                                \
                out[off] = hn;                                                \
                out[(size_t)8192 * 1024 + off] = cn;                          \
            }                                                                 \
        }                                                                     \
    } while (0)
    if (P == 0) EPI(0); else EPI(1);
#undef EPI
#undef ASB
#undef BSB
}

extern "C" void kernel_launch(void* const* d_in, const int* in_sizes, int n_in,
                              void* d_out, int out_size, void* d_ws, size_t ws_size,
                              hipStream_t stream) {
    const float* x = (const float*)d_in[0];
    const float* h = (const float*)d_in[1];
    const float* c = (const float*)d_in[2];
    const float* wi = (const float*)d_in[3];
    const float* bi = (const float*)d_in[4];
    const float* wh = (const float*)d_in[5];
    const float* bh = (const float*)d_in[6];
    const int* nbits = (const int*)d_in[7];
    float* out = (float*)d_out;

    char* ws = (char*)d_ws;
    float* params   = (float*)ws;                   // 8 f32
    float* partials = (float*)(ws + 64);            // 4*256*2 f32
    float* bc  = (float*)(ws + 16384);              // 4096 f32
    float* Rax = (float*)(ws + 32768);              // 8192 f32
    float* Rah = (float*)(ws + 65536);              // 8192 f32
    float* Rbi = (float*)(ws + 98304);              // 4096 f32
    float* Rbh = (float*)(ws + 114688);             // 4096 f32
    s8* A8 = (s8*)(ws + 131072);                    // 8192*2048 i8 = 16MB
    s8* W8 = (s8*)(ws + 131072 + (size_t)16 * 1024 * 1024);  // 4096*2048 i8 = 8MB

    k_minmax_partial<<<dim3(NB_RED, 4), 256, 0, stream>>>(x, h, wi, wh, partials);
    k_minmax_final<<<4, 256, 0, stream>>>(partials, nbits, params);
    k_quant<<<24592, 256, 0, stream>>>(x, h, wi, wh, params, bi, bh,
                                       A8, W8, Rax, Rah, Rbi, Rbh, bc);
    k_gemm_lstm<<<1024, 512, 0, stream>>>(A8, W8, params, bc, Rax, Rah, Rbi, Rbh, c, out);
}

// Round 19
// 135.246 us; speedup vs baseline: 1.2693x; 1.2693x over previous
//
#include <hip/hip_runtime.h>
#include <hip/hip_bf16.h>

typedef unsigned short u16;
typedef int i32x4 __attribute__((ext_vector_type(4)));
typedef int i32x16 __attribute__((ext_vector_type(16)));
typedef signed char s8;

#define NB_RED 256

static __device__ __forceinline__ float tanh_fast(float x) {
    float t = __expf(2.0f * x);
    return 1.0f - 2.0f / (t + 1.0f);
}

// ---------------- min/max reduction (4 tensors) ----------------
__global__ void k_minmax_partial(const float* __restrict__ x, const float* __restrict__ h,
                                 const float* __restrict__ wi, const float* __restrict__ wh,
                                 float* __restrict__ partials) {
    int t = blockIdx.y;
    const float* p = (t == 0) ? x : (t == 1) ? h : (t == 2) ? wi : wh;
    int n4 = ((t < 2) ? (8192 * 1024) : (4096 * 1024)) >> 2;
    float mn = 3.4e38f, mx = -3.4e38f;
    const float4* p4 = (const float4*)p;
    for (int i = blockIdx.x * blockDim.x + threadIdx.x; i < n4; i += gridDim.x * blockDim.x) {
        float4 v = p4[i];
        mn = fminf(mn, fminf(fminf(v.x, v.y), fminf(v.z, v.w)));
        mx = fmaxf(mx, fmaxf(fmaxf(v.x, v.y), fmaxf(v.z, v.w)));
    }
    for (int d = 1; d < 64; d <<= 1) {
        mn = fminf(mn, __shfl_xor(mn, d));
        mx = fmaxf(mx, __shfl_xor(mx, d));
    }
    __shared__ float smn[4], smx[4];
    int wv = threadIdx.x >> 6;
    if ((threadIdx.x & 63) == 0) { smn[wv] = mn; smx[wv] = mx; }
    __syncthreads();
    if (threadIdx.x == 0) {
        mn = fminf(fminf(smn[0], smn[1]), fminf(smn[2], smn[3]));
        mx = fmaxf(fmaxf(smx[0], smx[1]), fmaxf(smx[2], smx[3]));
        partials[(t * NB_RED + blockIdx.x) * 2 + 0] = mn;
        partials[(t * NB_RED + blockIdx.x) * 2 + 1] = mx;
    }
}

__global__ void k_minmax_final(const float* __restrict__ partials, const int* __restrict__ nbits,
                               float* __restrict__ params) {
    int t = blockIdx.x;
    int tid = threadIdx.x;
    float mn = partials[(t * NB_RED + tid) * 2 + 0];
    float mx = partials[(t * NB_RED + tid) * 2 + 1];
    for (int d = 1; d < 64; d <<= 1) {
        mn = fminf(mn, __shfl_xor(mn, d));
        mx = fmaxf(mx, __shfl_xor(mx, d));
    }
    __shared__ float smn[4], smx[4];
    int wv = tid >> 6;
    if ((tid & 63) == 0) { smn[wv] = mn; smx[wv] = mx; }
    __syncthreads();
    if (tid == 0) {
        mn = fminf(fminf(smn[0], smn[1]), fminf(smn[2], smn[3]));
        mx = fmaxf(fmaxf(smx[0], smx[1]), fmaxf(smx[2], smx[3]));
        float qmax = (float)((1u << (*nbits)) - 1u);
        params[t * 2 + 0] = mn;
        params[t * 2 + 1] = (mx - mn) / qmax;
    }
}

static __device__ __forceinline__ int block_reduce_i(int v, int tid) {
    for (int d = 1; d < 64; d <<= 1) v += __shfl_xor(v, d);
    __shared__ int sred[4];
    if ((tid & 63) == 0) sred[tid >> 6] = v;
    __syncthreads();
    return sred[0] + sred[1] + sred[2] + sred[3];
}

// ---- fused quantize (x|h -> A8, W_in|W_h -> W8 permuted) + bias ----
// W permutation (gate-PAIR form for 2x2 wave epilogue exchange):
//   original row = g*1024 + j  ->  prow = (j>>6)*256 + ((j>>5)&1)*128 + g*32 + (j&31)
__global__ void k_quant(const float* __restrict__ x, const float* __restrict__ h,
                        const float* __restrict__ wi, const float* __restrict__ wh,
                        const float* __restrict__ params,
                        const float* __restrict__ b_in, const float* __restrict__ b_h,
                        s8* __restrict__ A8, s8* __restrict__ W8,
                        float* __restrict__ Rax, float* __restrict__ Rah,
                        float* __restrict__ Rbi, float* __restrict__ Rbh,
                        float* __restrict__ bc) {
    int b = blockIdx.x;
    int t = threadIdx.x;
    if (b < 16384) {
        int tsel = b >> 13;            // 0: x, 1: h
        int row = b & 8191;
        const float* src = tsel ? h : x;
        float mn = params[tsel * 2 + 0], s = params[tsel * 2 + 1];
        float4 v = ((const float4*)(src + (size_t)row * 1024))[t];
        int k0 = (int)fminf(255.f, fmaxf(0.f, rintf((v.x - mn) / s)));
        int k1 = (int)fminf(255.f, fmaxf(0.f, rintf((v.y - mn) / s)));
        int k2 = (int)fminf(255.f, fmaxf(0.f, rintf((v.z - mn) / s)));
        int k3 = (int)fminf(255.f, fmaxf(0.f, rintf((v.w - mn) / s)));
        unsigned p = ((unsigned)((k0 - 128) & 0xff)) | ((unsigned)((k1 - 128) & 0xff) << 8) |
                     ((unsigned)((k2 - 128) & 0xff) << 16) | ((unsigned)((k3 - 128) & 0xff) << 24);
        *(unsigned*)(A8 + (size_t)row * 2048 + tsel * 1024 + t * 4) = p;
        int sum = block_reduce_i(k0 + k1 + k2 + k3 - 512, t);
        if (t == 0) (tsel ? Rah : Rax)[row] = (float)sum;
    } else if (b < 24576) {
        int bb = b - 16384;
        int tsel = bb >> 12;           // 0: W_in, 1: W_h
        int row = bb & 4095;           // original row g*1024+j
        const float* src = tsel ? wh : wi;
        float mn = params[(2 + tsel) * 2 + 0], s = params[(2 + tsel) * 2 + 1];
        int g = row >> 10, j = row & 1023;
        int prow = (j >> 6) * 256 + ((j >> 5) & 1) * 128 + g * 32 + (j & 31);
        float4 v = ((const float4*)(src + (size_t)row * 1024))[t];
        int k0 = (int)fminf(255.f, fmaxf(0.f, rintf((v.x - mn) / s)));
        int k1 = (int)fminf(255.f, fmaxf(0.f, rintf((v.y - mn) / s)));
        int k2 = (int)fminf(255.f, fmaxf(0.f, rintf((v.z - mn) / s)));
        int k3 = (int)fminf(255.f, fmaxf(0.f, rintf((v.w - mn) / s)));
        unsigned p = ((unsigned)((k0 - 128) & 0xff)) | ((unsigned)((k1 - 128) & 0xff) << 8) |
                     ((unsigned)((k2 - 128) & 0xff) << 16) | ((unsigned)((k3 - 128) & 0xff) << 24);
        *(unsigned*)(W8 + (size_t)prow * 2048 + tsel * 1024 + t * 4) = p;
        int sum = block_reduce_i(k0 + k1 + k2 + k3 - 512, t);
        if (t == 0) (tsel ? Rbh : Rbi)[prow] = (float)sum;
    } else {
        int n = (b - 24576) * 256 + t;   // permuted col index
        int tIdx = n >> 8, c = n & 255;
        int j = tIdx * 64 + ((c >> 7) & 1) * 32 + (c & 31);
        int g = (c >> 5) & 3;
        bc[n] = b_in[g * 1024 + j] + b_h[g * 1024 + j];
    }
}

// ------- fused i8 GEMM + LSTM (128x256, 2Mx4N waves of 64x64) ---------------
// = R17 exactly (session optimum: GEMM 104.8us, absmax 0.015625).
// R18's epilogue prefetch (cvv/rt, +32 live regs) spilled to scratch at the
// (512,4) 128-reg cap (WRITE_SIZE +57MB) -- reverted. Register headroom at
// this occupancy is ZERO; epilogue loads stay inline in EPI where the
// compiler schedules them within its budget.
// Structure: 128x256 tile, 8 waves (2M x 4N), wave 64x64 = 2x2 frags of
// 32x32, mfma_i32_32x32x32_i8; 3-buffer LDS ring, stage 2 ahead, counted
// vmcnt(3), ONE barrier per K-step; single acc + mid-K rescale t==16
// (r=csx/csh); swizzle f(r)=((r>>1)^(r>>3))&3 inverse-on-source; gate-pair
// W permutation + partner-wave LDS exchange epilogue; XCD decode grid 1024.
__global__ __launch_bounds__(512, 4) void k_gemm_lstm(
    const s8* __restrict__ A8, const s8* __restrict__ W8,
    const float* __restrict__ params, const float* __restrict__ bc,
    const float* __restrict__ Rax, const float* __restrict__ Rah,
    const float* __restrict__ Rbi, const float* __restrict__ Rbh,
    const float* __restrict__ c_in, float* __restrict__ out) {
    __shared__ __align__(16) s8 SH[73728];
#define ASB(B) (SH + (B) * 8192)
#define BSB(B) (SH + 24576 + (B) * 16384)

    const int tid = threadIdx.x;
    const int wave = tid >> 6, lane = tid & 63;
    const int wr = wave >> 2, wc = wave & 3;     // 2M x 4N wave grid
    const int l31 = lane & 31, lh = lane >> 5;

    const int bid = blockIdx.x;
    const int l = bid >> 3;                      // 0..127
    const int bx = l >> 3;                       // 0..15 (N tile, slow)
    const int by = (bid & 7) * 8 + (l & 7);      // 0..63 (M tile)
    const int bm = by * 128, bn = bx * 256;

    const int skb = (((tid & 3) ^ ((tid >> 3) & 3) ^ ((tid >> 5) & 3)) * 16);
    const int q = ((l31 >> 1) ^ (l31 >> 3)) & 3;

    const float sa = params[1], sh = params[3], si = params[5], sw = params[7];
    const float csx = sa * si, csh = sh * sw;
    const float r = csx / csh;

    const s8* pA0 = A8 + (size_t)(bm + (tid >> 2)) * 2048 + skb;
    const s8* pB0 = W8 + (size_t)(bn + (tid >> 2)) * 2048 + skb;
    const s8* pB1 = pB0 + (size_t)128 * 2048;

    i32x16 acc[2][2];
#pragma unroll
    for (int m = 0; m < 2; m++)
#pragma unroll
        for (int n = 0; n < 2; n++) acc[m][n] = (i32x16)0;

#define STAGE(B, T)                                                                               \
    do {                                                                                          \
        __builtin_amdgcn_global_load_lds(                                                         \
            (const __attribute__((address_space(1))) void*)(pA0 + (T) * 64),                      \
            (__attribute__((address_space(3))) void*)(ASB(B) + tid * 16), 16, 0, 0);              \
        __builtin_amdgcn_global_load_lds(                                                         \
            (const __attribute__((address_space(1))) void*)(pB0 + (T) * 64),                      \
            (__attribute__((address_space(3))) void*)(BSB(B) + tid * 16), 16, 0, 0);              \
        __builtin_amdgcn_global_load_lds(                                                         \
            (const __attribute__((address_space(1))) void*)(pB1 + (T) * 64),                      \
            (__attribute__((address_space(3))) void*)(BSB(B) + 8192 + tid * 16), 16, 0, 0);       \
    } while (0)

#define COMPUTE(B)                                                                                \
    do {                                                                                          \
        _Pragma("unroll") for (int ks = 0; ks < 2; ++ks) {                                        \
            const int ro = ((ks * 2 + lh) ^ q) * 16;                                              \
            i32x4 a0 = *(const i32x4*)(ASB(B) + (wr * 64 + l31) * 64 + ro);                       \
            i32x4 a1 = *(const i32x4*)(ASB(B) + (wr * 64 + 32 + l31) * 64 + ro);                  \
            i32x4 b0 = *(const i32x4*)(BSB(B) + (wc * 64 + l31) * 64 + ro);                       \
            i32x4 b1 = *(const i32x4*)(BSB(B) + (wc * 64 + 32 + l31) * 64 + ro);                  \
            acc[0][0] = __builtin_amdgcn_mfma_i32_32x32x32_i8(a0, b0, acc[0][0], 0, 0, 0);        \
            acc[0][1] = __builtin_amdgcn_mfma_i32_32x32x32_i8(a0, b1, acc[0][1], 0, 0, 0);        \
            acc[1][0] = __builtin_amdgcn_mfma_i32_32x32x32_i8(a1, b0, acc[1][0], 0, 0, 0);        \
            acc[1][1] = __builtin_amdgcn_mfma_i32_32x32x32_i8(a1, b1, acc[1][1], 0, 0, 0);        \
        }                                                                                         \
    } while (0)

    STAGE(0, 0);
    STAGE(1, 1);
    asm volatile("s_waitcnt vmcnt(3)" ::: "memory");
    __builtin_amdgcn_s_barrier();

#pragma unroll
    for (int t = 0; t < 32; ++t) {
        if (t < 30) STAGE((t + 2) % 3, t + 2);
        if (t == 16) {
#pragma unroll
            for (int m = 0; m < 2; m++)
#pragma unroll
                for (int n = 0; n < 2; n++)
#pragma unroll
                    for (int e = 0; e < 16; e++)
                        acc[m][n][e] = (int)rintf((float)acc[m][n][e] * r);
        }
        COMPUTE(t % 3);
        if (t < 30) { asm volatile("s_waitcnt vmcnt(3)" ::: "memory"); }
        else if (t == 30) { asm volatile("s_waitcnt vmcnt(0)" ::: "memory"); }
        if (t < 31) __builtin_amdgcn_s_barrier();
    }

#undef STAGE
#undef COMPUTE

    // ---- epilogue: partner-wave gate exchange through LDS, then LSTM ----
    __syncthreads();   // all waves done reading K-loop buffers

    const int P = wc & 1;            // own gate pair; also own output row-half
    const int l7 = lane & 7;
    s8* xw = SH + wave * 8192 + lane * 128;          // own slot (64KB total)
    s8* xr = SH + (wave ^ 1) * 8192 + lane * 128;    // partner slot

#define WRX(MIP)                                                              \
    do {                                                                      \
        _Pragma("unroll") for (int ni = 0; ni < 2; ++ni)                      \
            _Pragma("unroll") for (int c2 = 0; c2 < 4; ++c2) {                \
                i32x4 v;                                                      \
                v[0] = acc[MIP][ni][4 * c2 + 0];                              \
                v[1] = acc[MIP][ni][4 * c2 + 1];                              \
                v[2] = acc[MIP][ni][4 * c2 + 2];                              \
                v[3] = acc[MIP][ni][4 * c2 + 3];                              \
                *(i32x4*)(xw + (((ni * 4 + c2) ^ l7) * 16)) = v;              \
            }                                                                 \
    } while (0)
    if (P == 0) WRX(1); else WRX(0);
#undef WRX

    __syncthreads();   // partner writes visible

    float mna = params[0], mnh = params[2], mni = params[4], mnw = params[6];
    float za = mna + 128.0f * sa, zi = mni + 128.0f * si;
    float zh = mnh + 128.0f * sh, zw = mnw + 128.0f * sw;
    float C0 = 1024.0f * (za * zi + zh * zw);
    float cax = sa * zi, cah = sh * zw;
    float cbx = si * za, cbh = sw * zh;

    float colt[4];
#pragma unroll
    for (int g = 0; g < 4; ++g) {
        int np = bn + (wc >> 1) * 128 + g * 32 + l31;
        colt[g] = bc[np] + cbx * Rbi[np] + cbh * Rbh[np] + C0;
    }
    const int ub = (bn >> 2) + (wc >> 1) * 32 + l31;   // hidden-unit index

#define EPI(MIO)                                                              \
    do {                                                                      \
        _Pragma("unroll") for (int c2 = 0; c2 < 4; ++c2) {                    \
            i32x4 q0 = *(const i32x4*)(xr + (((c2) ^ l7) * 16));              \
            i32x4 q1 = *(const i32x4*)(xr + (((4 + c2) ^ l7) * 16));          \
            _Pragma("unroll") for (int e = 0; e < 4; ++e) {                   \
                int row = bm + wr * 64 + (MIO) * 32 + 8 * c2 + 4 * lh + e;    \
                float rterm = cax * Rax[row] + cah * Rah[row];                \
                float gv0, gv1, gv2, gv3;                                     \
                if ((MIO) == 0) {                                             \
                    gv0 = (float)acc[0][0][4 * c2 + e];                       \
                    gv1 = (float)acc[0][1][4 * c2 + e];                       \
                    gv2 = (float)q0[e]; gv3 = (float)q1[e];                   \
                } else {                                                      \
                    gv2 = (float)acc[1][0][4 * c2 + e];                       \
                    gv3 = (float)acc[1][1][4 * c2 + e];                       \
                    gv0 = (float)q0[e]; gv1 = (float)q1[e];                   \
                }                                                             \
                float g0 = colt[0] + rterm + csh * gv0;                       \
                float g1 = colt[1] + rterm + csh * gv1;                       \
                float g2 = colt[2] + rterm + csh * gv2;                       \
                float g3 = colt[3] + rterm + csh * gv3;                       \
                float iv = 1.0f / (1.0f + __expf(-g0));                       \
                float fv = 1.0f / (1.0f + __expf(-g1));                       \
                float gg = tanh_fast(g2);                                     \
                float ov = 1.0f / (1.0f + __expf(-g3));                       \
                size_t off = (size_t)row * 1024 + ub;                         \
                float cv = c_in[off];                                         \
                float cn = fv * cv + iv * gg;                                 \
                float hn = ov * tanh_fast(cn);                                \
                out[off] = hn;                                                \
                out[(size_t)8192 * 1024 + off] = cn;                          \
            }                                                                 \
        }                                                                     \
    } while (0)
    if (P == 0) EPI(0); else EPI(1);
#undef EPI
#undef ASB
#undef BSB
}

extern "C" void kernel_launch(void* const* d_in, const int* in_sizes, int n_in,
                              void* d_out, int out_size, void* d_ws, size_t ws_size,
                              hipStream_t stream) {
    const float* x = (const float*)d_in[0];
    const float* h = (const float*)d_in[1];
    const float* c = (const float*)d_in[2];
    const float* wi = (const float*)d_in[3];
    const float* bi = (const float*)d_in[4];
    const float* wh = (const float*)d_in[5];
    const float* bh = (const float*)d_in[6];
    const int* nbits = (const int*)d_in[7];
    float* out = (float*)d_out;

    char* ws = (char*)d_ws;
    float* params   = (float*)ws;                   // 8 f32
    float* partials = (float*)(ws + 64);            // 4*256*2 f32
    float* bc  = (float*)(ws + 16384);              // 4096 f32
    float* Rax = (float*)(ws + 32768);              // 8192 f32
    float* Rah = (float*)(ws + 65536);              // 8192 f32
    float* Rbi = (float*)(ws + 98304);              // 4096 f32
    float* Rbh = (float*)(ws + 114688);             // 4096 f32
    s8* A8 = (s8*)(ws + 131072);                    // 8192*2048 i8 = 16MB
    s8* W8 = (s8*)(ws + 131072 + (size_t)16 * 1024 * 1024);  // 4096*2048 i8 = 8MB

    k_minmax_partial<<<dim3(NB_RED, 4), 256, 0, stream>>>(x, h, wi, wh, partials);
    k_minmax_final<<<4, 256, 0, stream>>>(partials, nbits, params);
    k_quant<<<24592, 256, 0, stream>>>(x, h, wi, wh, params, bi, bh,
                                       A8, W8, Rax, Rah, Rbi, Rbh, bc);
    k_gemm_lstm<<<1024, 512, 0, stream>>>(A8, W8, params, bc, Rax, Rah, Rbi, Rbh, c, out);
}